// Round 15
// baseline (187.868 us; speedup 1.0000x reference)
//
#include <hip/hip_runtime.h>
#include <hip/hip_bf16.h>

#define BT 16384      // B*T rows
#define CDIM 1024
#define HD 64
#define TT 4096

typedef __bf16 bf16x8 __attribute__((ext_vector_type(8)));
typedef __bf16 bf16x4 __attribute__((ext_vector_type(4)));
typedef float f32x4 __attribute__((ext_vector_type(4)));

__device__ __forceinline__ f32x4 mfma16(bf16x8 a, bf16x8 b, f32x4 c){
  return __builtin_amdgcn_mfma_f32_16x16x32_bf16(a, b, c, 0, 0, 0);
}

// ---------- kernel 1: weights -> bf16 [192][1024]; Wq rows pre-scaled by 1/8.
// Block 0 also zeroes the 256 split-completion counters (stream-ordered before attn).
__global__ __launch_bounds__(256) void wconv_k(const float* __restrict__ Wk,
    const float* __restrict__ Wq, const float* __restrict__ Wv,
    __bf16* __restrict__ Wbf, int* __restrict__ cnt){
  if (blockIdx.x == 0) cnt[threadIdx.x] = 0;
  int idx = blockIdx.x*256 + threadIdx.x;
  int e0 = idx*4;
  int n = e0 >> 10;
  int c = e0 & 1023;
  const float* src; float s;
  if (n < 64)      { src = Wk + (size_t)n*CDIM;       s = 1.0f;   }
  else if (n < 128){ src = Wq + (size_t)(n-64)*CDIM;  s = 0.125f; }
  else             { src = Wv + (size_t)(n-128)*CDIM; s = 1.0f;   }
  float4 v = *reinterpret_cast<const float4*>(src + c);
  __bf16* dst = Wbf + e0;
  dst[0]=(__bf16)(v.x*s); dst[1]=(__bf16)(v.y*s);
  dst[2]=(__bf16)(v.z*s); dst[3]=(__bf16)(v.w*s);
}

// ---------- kernel 2: projections (r9 best: single-barrier dbuf, depth-1 reg lead).
// grid 512 x 512 thr (8 waves), M-tile 32, K=1024 in 16 steps of 64.
__global__ __launch_bounds__(512) void proj_k(const float* __restrict__ x,
    const __bf16* __restrict__ Wbf, __bf16* __restrict__ kb,
    __bf16* __restrict__ qb, __bf16* __restrict__ vTb){
  __shared__ __bf16 Wt[2][192][68];   // 51.0 KB
  __shared__ __bf16 Xt[2][32][68];    //  8.5 KB

  const int tid  = threadIdx.x;
  const int lane = tid & 63;
  const int w    = tid >> 6;        // 0..7
  const int wr   = w >> 2;          // row half (16 rows each)
  const int wn   = w & 3;           // N quarter (48 cols each)
  const int l15  = lane & 15, g = lane >> 4;
  const long row0 = (long)blockIdx.x*32;

  const int wrw0 = tid>>3, wrw1 = (tid+512)>>3, wrw2 = (tid+1024)>>3;
  const int wc8  = (tid & 7)*8;
  const int xrw  = tid >> 4, xc4 = (tid & 15)*4;

  const float*  xsrc = x + (row0 + xrw)*CDIM + xc4;
  const __bf16* ws0  = Wbf + (size_t)wrw0*CDIM + wc8;
  const __bf16* ws1  = Wbf + (size_t)wrw1*CDIM + wc8;
  const __bf16* ws2  = Wbf + (size_t)wrw2*CDIM + wc8;

  f32x4 acc[3];
  #pragma unroll
  for (int j=0;j<3;j++) acc[j] = (f32x4)(0.0f);

  bf16x8 w0, w1, w2; float4 xr;

  // prologue: tile 0 -> regs -> buf0; tile 1 -> regs; barrier
  w0 = *reinterpret_cast<const bf16x8*>(ws0);
  w1 = *reinterpret_cast<const bf16x8*>(ws1);
  w2 = *reinterpret_cast<const bf16x8*>(ws2);
  xr = *reinterpret_cast<const float4*>(xsrc);
  *reinterpret_cast<bf16x8*>(&Wt[0][wrw0][wc8]) = w0;
  *reinterpret_cast<bf16x8*>(&Wt[0][wrw1][wc8]) = w1;
  *reinterpret_cast<bf16x8*>(&Wt[0][wrw2][wc8]) = w2;
  {
    bf16x4 xv;
    xv[0]=(__bf16)xr.x; xv[1]=(__bf16)xr.y; xv[2]=(__bf16)xr.z; xv[3]=(__bf16)xr.w;
    *reinterpret_cast<bf16x4*>(&Xt[0][xrw][xc4]) = xv;
  }
  w0 = *reinterpret_cast<const bf16x8*>(ws0 + 64);
  w1 = *reinterpret_cast<const bf16x8*>(ws1 + 64);
  w2 = *reinterpret_cast<const bf16x8*>(ws2 + 64);
  xr = *reinterpret_cast<const float4*>(xsrc + 64);
  __syncthreads();

  #pragma unroll 2
  for (int t=0; t<16; ++t){
    const int cur = t & 1, nxt = cur ^ 1;

    if (t+1 < 16){
      *reinterpret_cast<bf16x8*>(&Wt[nxt][wrw0][wc8]) = w0;
      *reinterpret_cast<bf16x8*>(&Wt[nxt][wrw1][wc8]) = w1;
      *reinterpret_cast<bf16x8*>(&Wt[nxt][wrw2][wc8]) = w2;
      bf16x4 xv;
      xv[0]=(__bf16)xr.x; xv[1]=(__bf16)xr.y; xv[2]=(__bf16)xr.z; xv[3]=(__bf16)xr.w;
      *reinterpret_cast<bf16x4*>(&Xt[nxt][xrw][xc4]) = xv;
    }
    if (t+2 < 16){
      const int nk0 = (t+2)*64;
      w0 = *reinterpret_cast<const bf16x8*>(ws0 + nk0);
      w1 = *reinterpret_cast<const bf16x8*>(ws1 + nk0);
      w2 = *reinterpret_cast<const bf16x8*>(ws2 + nk0);
      xr = *reinterpret_cast<const float4*>(xsrc + nk0);
    }
    {
      bf16x8 a0 = *reinterpret_cast<const bf16x8*>(&Xt[cur][wr*16 + l15][g*8]);
      bf16x8 a1 = *reinterpret_cast<const bf16x8*>(&Xt[cur][wr*16 + l15][g*8 + 32]);
      bf16x8 b0[3], b1[3];
      #pragma unroll
      for (int nf=0;nf<3;nf++){
        b0[nf] = *reinterpret_cast<const bf16x8*>(&Wt[cur][wn*48 + nf*16 + l15][g*8]);
        b1[nf] = *reinterpret_cast<const bf16x8*>(&Wt[cur][wn*48 + nf*16 + l15][g*8 + 32]);
      }
      #pragma unroll
      for (int nf=0;nf<3;nf++)
        acc[nf] = mfma16(a1, b1[nf], mfma16(a0, b0[nf], acc[nf]));
    }
    __syncthreads();
  }

  // epilogue: k,q row-major [BT][64]; v transposed [B][64][T]
  const long bidx = row0 >> 12;
  #pragma unroll
  for (int nf=0;nf<3;nf++){
    const int n0  = wn*48 + nf*16 + l15;
    const int mat = n0 >> 6;
    const int h   = n0 & 63;
    const long rbase = row0 + wr*16 + g*4;
    if (mat == 0){
      #pragma unroll
      for (int r=0;r<4;r++) kb[(rbase+r)*HD + h] = (__bf16)acc[nf][r];
    } else if (mat == 1){
      #pragma unroll
      for (int r=0;r<4;r++) qb[(rbase+r)*HD + h] = (__bf16)acc[nf][r];
    } else {
      bf16x4 t4;
      #pragma unroll
      for (int r=0;r<4;r++) t4[r] = (__bf16)acc[nf][r];
      *reinterpret_cast<bf16x4*>(vTb + (bidx*64 + h)*TT + (rbase & 4095)) = t4;
    }
  }
}

// ---------- kernel 3: causal flash attention with FUSED split-K combine.
// r9 config: QBLK=64, 4 waves, fixed-max softmax, reg-prefetched staging, NS splits.
// Last split block of each (b,qt) group (device atomics) combines and writes out.
template<int NS>
__global__ __launch_bounds__(256) void attn_part_k(const __bf16* __restrict__ kbg,
    const __bf16* __restrict__ qbg, const __bf16* __restrict__ vT,
    __bf16* __restrict__ po, float* __restrict__ pl,
    int* __restrict__ cnt, float* __restrict__ out){
  __shared__ __bf16 Klds[64][68];
  __shared__ __bf16 Vlds[64][68];
  __shared__ __bf16 Plds[4][16][68];
  __shared__ float  plb[NS][64];
  __shared__ float  rden[64];
  __shared__ int    winner;

  const int tid  = threadIdx.x;
  const int lane = tid & 63;
  const int w    = tid >> 6;
  const int l15  = lane & 15, g = lane >> 4;

  const int bi  = blockIdx.x;
  const int b   = bi / (64*NS);
  const int rem = bi % (64*NS);
  const int qt  = 63 - rem / NS;      // longest blocks dispatch first
  const int s   = rem % NS;

  const int ntiles = qt + 1;
  const int lo = ( s      * ntiles) / NS;
  const int hi = ((s + 1) * ntiles) / NS;
  const int grp  = b*64 + qt;
  const int pidx = grp*NS + s;

  if (lo == hi){                      // empty split: weight 0
    if (l15 == 0){
      #pragma unroll
      for (int r=0;r<4;r++) pl[pidx*64 + w*16 + g*4 + r] = 0.0f;
    }
  } else {

  const long qbase = (long)b*TT + (long)qt*64;

  bf16x8 qf0, qf1;
  {
    const __bf16* src = qbg + (qbase + w*16 + l15)*HD + g*8;
    qf0 = *reinterpret_cast<const bf16x8*>(src);
    qf1 = *reinterpret_cast<const bf16x8*>(src + 32);
  }

  f32x4 o[4];
  #pragma unroll
  for (int ch=0; ch<4; ++ch) o[ch] = (f32x4)(0.0f);
  float lp[4] = {0.f, 0.f, 0.f, 0.f};

  const __bf16* vbase = vT + (size_t)b*64*TT;

  const int skey = tid >> 2;
  const int sd0  = (tid & 3) * 16;
  bf16x8 kr0, kr1, vr0, vr1;

  {
    const long kvbase = (long)b*TT + (long)lo*64;
    const __bf16* ks = kbg + (kvbase + skey)*HD + sd0;
    kr0 = *reinterpret_cast<const bf16x8*>(ks);
    kr1 = *reinterpret_cast<const bf16x8*>(ks+8);
    const __bf16* vs = vbase + (size_t)skey*TT + lo*64 + sd0;
    vr0 = *reinterpret_cast<const bf16x8*>(vs);
    vr1 = *reinterpret_cast<const bf16x8*>(vs+8);
  }

  for (int kv=lo; kv<hi; ++kv){
    __syncthreads();
    *reinterpret_cast<bf16x8*>(&Klds[skey][sd0])   = kr0;
    *reinterpret_cast<bf16x8*>(&Klds[skey][sd0+8]) = kr1;
    *reinterpret_cast<bf16x8*>(&Vlds[skey][sd0])   = vr0;
    *reinterpret_cast<bf16x8*>(&Vlds[skey][sd0+8]) = vr1;
    __syncthreads();

    if (kv+1 < hi){
      const long nbase = (long)b*TT + (long)(kv+1)*64;
      const __bf16* ks = kbg + (nbase + skey)*HD + sd0;
      kr0 = *reinterpret_cast<const bf16x8*>(ks);
      kr1 = *reinterpret_cast<const bf16x8*>(ks+8);
      const __bf16* vs = vbase + (size_t)skey*TT + (kv+1)*64 + sd0;
      vr0 = *reinterpret_cast<const bf16x8*>(vs);
      vr1 = *reinterpret_cast<const bf16x8*>(vs+8);
    }

    f32x4 sv[4];
    __builtin_amdgcn_s_setprio(1);
    #pragma unroll
    for (int c=0;c<4;c++){
      bf16x8 kb0 = *reinterpret_cast<const bf16x8*>(&Klds[c*16 + l15][g*8]);
      bf16x8 kb1 = *reinterpret_cast<const bf16x8*>(&Klds[c*16 + l15][g*8 + 32]);
      sv[c] = mfma16(qf0, kb0, (f32x4)(-16.0f));
      sv[c] = mfma16(qf1, kb1, sv[c]);
    }
    __builtin_amdgcn_s_setprio(0);

    if (kv == qt){
      #pragma unroll
      for (int c=0;c<4;c++){
        const int key = c*16 + l15;
        #pragma unroll
        for (int r=0;r<4;r++){
          const int qr = w*16 + g*4 + r;
          if (key > qr) sv[c][r] = -1e30f;
        }
      }
    }

    #pragma unroll
    for (int c=0;c<4;c++){
      #pragma unroll
      for (int r=0;r<4;r++) sv[c][r] = __expf(sv[c][r]);
    }
    #pragma unroll
    for (int r=0;r<4;r++)
      lp[r] += (sv[0][r] + sv[1][r]) + (sv[2][r] + sv[3][r]);

    #pragma unroll
    for (int c=0;c<4;c++){
      #pragma unroll
      for (int r=0;r<4;r++) Plds[w][g*4+r][c*16 + l15] = (__bf16)sv[c][r];
    }
    asm volatile("s_waitcnt lgkmcnt(0)" ::: "memory");
    __builtin_amdgcn_sched_barrier(0);
    bf16x8 pa0 = *reinterpret_cast<const bf16x8*>(&Plds[w][l15][g*8]);
    bf16x8 pa1 = *reinterpret_cast<const bf16x8*>(&Plds[w][l15][g*8 + 32]);

    __builtin_amdgcn_s_setprio(1);
    #pragma unroll
    for (int ch=0; ch<4; ++ch){
      bf16x8 vb0 = *reinterpret_cast<const bf16x8*>(&Vlds[ch*16 + l15][g*8]);
      bf16x8 vb1 = *reinterpret_cast<const bf16x8*>(&Vlds[ch*16 + l15][g*8 + 32]);
      o[ch] = mfma16(pa0, vb0, o[ch]);
      o[ch] = mfma16(pa1, vb1, o[ch]);
    }
    __builtin_amdgcn_s_setprio(0);
  }

  float lr[4];
  #pragma unroll
  for (int r=0;r<4;r++){
    float v = lp[r];
    v += __shfl_xor(v, 1);
    v += __shfl_xor(v, 2);
    v += __shfl_xor(v, 4);
    v += __shfl_xor(v, 8);
    lr[r] = v;
  }
  float rl[4];
  #pragma unroll
  for (int r=0;r<4;r++) rl[r] = (lr[r] > 0.0f) ? 1.0f/lr[r] : 0.0f;

  __bf16* podst = po + (size_t)pidx*4096;
  #pragma unroll
  for (int ch=0; ch<4; ++ch){
    #pragma unroll
    for (int r=0;r<4;r++)
      podst[(w*16 + g*4 + r)*64 + ch*16 + l15] = (__bf16)(o[ch][r] * rl[r]);
  }
  if (l15 == 0){
    #pragma unroll
    for (int r=0;r<4;r++) pl[pidx*64 + w*16 + g*4 + r] = lr[r];
  }

  }  // end non-empty split

  // ---- fused split-K combine: last-arriving block of the group does it
  __syncthreads();
  if (tid == 0){
    __threadfence();                           // release po/pl
    int c = atomicAdd(&cnt[grp], 1);
    if (c == NS-1){ __threadfence(); winner = 1; }   // acquire
    else winner = 0;
  }
  __syncthreads();
  if (!winner) return;

  if (tid < 64){
    float d = 0.f;
    #pragma unroll
    for (int s2=0;s2<NS;s2++){
      float lv = pl[(grp*NS + s2)*64 + tid];
      plb[s2][tid] = lv;
      d += lv;
    }
    rden[tid] = 1.0f/d;
  }
  __syncthreads();
  const __bf16* pog = po + (size_t)grp*NS*4096;
  float* og = out + ((long)b*TT + (long)qt*64)*64;
  #pragma unroll 4
  for (int e = tid; e < 4096; e += 256){
    const int row = e >> 6;
    float num = 0.f;
    #pragma unroll
    for (int s2=0;s2<NS;s2++)
      num += plb[s2][row] * (float)pog[s2*4096 + e];
    og[e] = num * rden[row];
  }
}

extern "C" void kernel_launch(void* const* d_in, const int* in_sizes, int n_in,
                              void* d_out, int out_size, void* d_ws, size_t ws_size,
                              hipStream_t stream) {
  const float* x  = (const float*)d_in[0];
  const float* Wk = (const float*)d_in[2];
  const float* Wq = (const float*)d_in[3];
  const float* Wv = (const float*)d_in[4];
  float* out = (float*)d_out;

  char* ws = (char*)d_ws;
  __bf16* Wbf = (__bf16*)ws;                         // 384 KiB
  __bf16* kb  = (__bf16*)(ws + 393216);              // 2 MiB
  __bf16* qb  = (__bf16*)(ws + 2490368);             // 2 MiB
  __bf16* vTb = (__bf16*)(ws + 4587520);             // 2 MiB
  __bf16* po  = (__bf16*)(ws + 6684672);

  const size_t need8 = 6684672ull + (size_t)2048*4096*2 + (size_t)2048*64*4 + 1024;
  if (ws_size >= need8){
    float* pl  = (float*)(ws + 6684672 + (size_t)2048*4096*2);
    int*   cnt = (int*)  (ws + 6684672 + (size_t)2048*4096*2 + (size_t)2048*64*4);
    wconv_k     <<<192,  256, 0, stream>>>(Wk, Wq, Wv, Wbf, cnt);
    proj_k      <<<512,  512, 0, stream>>>(x, Wbf, kb, qb, vTb);
    attn_part_k<8><<<2048, 256, 0, stream>>>(kb, qb, vTb, po, pl, cnt, out);
  } else {
    float* pl  = (float*)(ws + 6684672 + (size_t)1024*4096*2);
    int*   cnt = (int*)  (ws + 6684672 + (size_t)1024*4096*2 + (size_t)1024*64*4);
    wconv_k     <<<192,  256, 0, stream>>>(Wk, Wq, Wv, Wbf, cnt);
    proj_k      <<<512,  512, 0, stream>>>(x, Wbf, kb, qb, vTb);
    attn_part_k<4><<<1024, 256, 0, stream>>>(kb, qb, vTb, po, pl, cnt, out);
  }
}

// Round 16
// 59.849 us; speedup vs baseline: 3.1390x; 3.1390x over previous
//
#include <hip/hip_runtime.h>
#include <hip/hip_bf16.h>

#define BT 16384      // B*T rows
#define CDIM 1024
#define HD 64
#define TT 4096

typedef __bf16 bf16x8 __attribute__((ext_vector_type(8)));
typedef __bf16 bf16x4 __attribute__((ext_vector_type(4)));
typedef float f32x4 __attribute__((ext_vector_type(4)));

__device__ __forceinline__ f32x4 mfma16(bf16x8 a, bf16x8 b, f32x4 c){
  return __builtin_amdgcn_mfma_f32_16x16x32_bf16(a, b, c, 0, 0, 0);
}

__device__ __forceinline__ bf16x8 cvt8(float4 lo, float4 hi, float s){
  bf16x8 v;
  v[0]=(__bf16)(lo.x*s); v[1]=(__bf16)(lo.y*s); v[2]=(__bf16)(lo.z*s); v[3]=(__bf16)(lo.w*s);
  v[4]=(__bf16)(hi.x*s); v[5]=(__bf16)(hi.y*s); v[6]=(__bf16)(hi.z*s); v[7]=(__bf16)(hi.w*s);
  return v;
}

// ---------- kernel 1: projections with FUSED weight conversion (wconv eliminated).
// r9 structure: grid 512 x 512 thr (8 waves), M-tile 32, K=1024 in 16 steps of 64,
// single-barrier dbuf, depth-1 reg lead. W staged from f32 Wk/Wq/Wv directly,
// converted (and 1/8-scaled for Wq) during the ds_write.
__global__ __launch_bounds__(512) void proj_k(const float* __restrict__ x,
    const float* __restrict__ Wk, const float* __restrict__ Wq,
    const float* __restrict__ Wv, __bf16* __restrict__ kb,
    __bf16* __restrict__ qb, __bf16* __restrict__ vTb){
  __shared__ __bf16 Wt[2][192][68];   // 51.0 KB
  __shared__ __bf16 Xt[2][32][68];    //  8.5 KB

  const int tid  = threadIdx.x;
  const int lane = tid & 63;
  const int w    = tid >> 6;        // 0..7
  const int wr   = w >> 2;          // row half (16 rows each)
  const int wn   = w & 3;           // N quarter (48 cols each)
  const int l15  = lane & 15, g = lane >> 4;
  const long row0 = (long)blockIdx.x*32;

  // staging slots: 3 W rows (one per 64-row band) + 1 x float4 per thread
  const int wrw0 = tid>>3, wrw1 = (tid+512)>>3, wrw2 = (tid+1024)>>3;
  const int wc8  = (tid & 7)*8;
  const int xrw  = tid >> 4, xc4 = (tid & 15)*4;

  const float* xsrc = x + (row0 + xrw)*CDIM + xc4;
  const float* wsf0 = Wk + (size_t)wrw0*CDIM + wc8;            // rows 0..63, s=1
  const float* wsf1 = Wq + (size_t)(wrw1-64)*CDIM + wc8;       // rows 64..127, s=1/8
  const float* wsf2 = Wv + (size_t)(wrw2-128)*CDIM + wc8;      // rows 128..191, s=1

  f32x4 acc[3];
  #pragma unroll
  for (int j=0;j<3;j++) acc[j] = (f32x4)(0.0f);

  float4 w0a,w0b,w1a,w1b,w2a,w2b, xr;

  // prologue: tile 0 -> regs -> buf0; tile 1 -> regs; barrier
  w0a = *reinterpret_cast<const float4*>(wsf0);
  w0b = *reinterpret_cast<const float4*>(wsf0 + 4);
  w1a = *reinterpret_cast<const float4*>(wsf1);
  w1b = *reinterpret_cast<const float4*>(wsf1 + 4);
  w2a = *reinterpret_cast<const float4*>(wsf2);
  w2b = *reinterpret_cast<const float4*>(wsf2 + 4);
  xr  = *reinterpret_cast<const float4*>(xsrc);
  *reinterpret_cast<bf16x8*>(&Wt[0][wrw0][wc8]) = cvt8(w0a, w0b, 1.0f);
  *reinterpret_cast<bf16x8*>(&Wt[0][wrw1][wc8]) = cvt8(w1a, w1b, 0.125f);
  *reinterpret_cast<bf16x8*>(&Wt[0][wrw2][wc8]) = cvt8(w2a, w2b, 1.0f);
  {
    bf16x4 xv;
    xv[0]=(__bf16)xr.x; xv[1]=(__bf16)xr.y; xv[2]=(__bf16)xr.z; xv[3]=(__bf16)xr.w;
    *reinterpret_cast<bf16x4*>(&Xt[0][xrw][xc4]) = xv;
  }
  w0a = *reinterpret_cast<const float4*>(wsf0 + 64);
  w0b = *reinterpret_cast<const float4*>(wsf0 + 68);
  w1a = *reinterpret_cast<const float4*>(wsf1 + 64);
  w1b = *reinterpret_cast<const float4*>(wsf1 + 68);
  w2a = *reinterpret_cast<const float4*>(wsf2 + 64);
  w2b = *reinterpret_cast<const float4*>(wsf2 + 68);
  xr  = *reinterpret_cast<const float4*>(xsrc + 64);
  __syncthreads();

  #pragma unroll 2
  for (int t=0; t<16; ++t){
    const int cur = t & 1, nxt = cur ^ 1;

    // (a) write tile t+1 (regs loaded a full iteration ago)
    if (t+1 < 16){
      *reinterpret_cast<bf16x8*>(&Wt[nxt][wrw0][wc8]) = cvt8(w0a, w0b, 1.0f);
      *reinterpret_cast<bf16x8*>(&Wt[nxt][wrw1][wc8]) = cvt8(w1a, w1b, 0.125f);
      *reinterpret_cast<bf16x8*>(&Wt[nxt][wrw2][wc8]) = cvt8(w2a, w2b, 1.0f);
      bf16x4 xv;
      xv[0]=(__bf16)xr.x; xv[1]=(__bf16)xr.y; xv[2]=(__bf16)xr.z; xv[3]=(__bf16)xr.w;
      *reinterpret_cast<bf16x4*>(&Xt[nxt][xrw][xc4]) = xv;
    }
    // (b) issue tile t+2 loads
    if (t+2 < 16){
      const int nk0 = (t+2)*64;
      w0a = *reinterpret_cast<const float4*>(wsf0 + nk0);
      w0b = *reinterpret_cast<const float4*>(wsf0 + nk0 + 4);
      w1a = *reinterpret_cast<const float4*>(wsf1 + nk0);
      w1b = *reinterpret_cast<const float4*>(wsf1 + nk0 + 4);
      w2a = *reinterpret_cast<const float4*>(wsf2 + nk0);
      w2b = *reinterpret_cast<const float4*>(wsf2 + nk0 + 4);
      xr  = *reinterpret_cast<const float4*>(xsrc + nk0);
    }
    // (c) compute tile t from buf[cur]
    {
      bf16x8 a0 = *reinterpret_cast<const bf16x8*>(&Xt[cur][wr*16 + l15][g*8]);
      bf16x8 a1 = *reinterpret_cast<const bf16x8*>(&Xt[cur][wr*16 + l15][g*8 + 32]);
      bf16x8 b0[3], b1[3];
      #pragma unroll
      for (int nf=0;nf<3;nf++){
        b0[nf] = *reinterpret_cast<const bf16x8*>(&Wt[cur][wn*48 + nf*16 + l15][g*8]);
        b1[nf] = *reinterpret_cast<const bf16x8*>(&Wt[cur][wn*48 + nf*16 + l15][g*8 + 32]);
      }
      #pragma unroll
      for (int nf=0;nf<3;nf++)
        acc[nf] = mfma16(a1, b1[nf], mfma16(a0, b0[nf], acc[nf]));
    }
    // (d) one barrier per step
    __syncthreads();
  }

  // epilogue: k,q row-major [BT][64]; v transposed [B][64][T]
  const long bidx = row0 >> 12;            // batch (32 | 4096, never crosses)
  #pragma unroll
  for (int nf=0;nf<3;nf++){
    const int n0  = wn*48 + nf*16 + l15;
    const int mat = n0 >> 6;               // 0=k, 1=q, 2=v
    const int h   = n0 & 63;
    const long rbase = row0 + wr*16 + g*4;
    if (mat == 0){
      #pragma unroll
      for (int r=0;r<4;r++) kb[(rbase+r)*HD + h] = (__bf16)acc[nf][r];
    } else if (mat == 1){
      #pragma unroll
      for (int r=0;r<4;r++) qb[(rbase+r)*HD + h] = (__bf16)acc[nf][r];
    } else {
      bf16x4 t4;
      #pragma unroll
      for (int r=0;r<4;r++) t4[r] = (__bf16)acc[nf][r];
      *reinterpret_cast<bf16x4*>(vTb + (bidx*64 + h)*TT + (rbase & 4095)) = t4;
    }
  }
}

// ---------- kernel 2: causal flash attention (byte-identical to r9 best config).
// QBLK=64, fixed-max softmax, KV-split partials, reg-prefetched staging.
template<int NS>
__global__ __launch_bounds__(256) void attn_part_k(const __bf16* __restrict__ kbg,
    const __bf16* __restrict__ qbg, const __bf16* __restrict__ vT,
    __bf16* __restrict__ po, float* __restrict__ pl){
  __shared__ __bf16 Klds[64][68];     // [key][dim]
  __shared__ __bf16 Vlds[64][68];     // [dim][key]  (from pre-transposed vT)
  __shared__ __bf16 Plds[4][16][68];  // per-wave P round-trip

  const int tid  = threadIdx.x;
  const int lane = tid & 63;
  const int w    = tid >> 6;
  const int l15  = lane & 15, g = lane >> 4;

  const int bi  = blockIdx.x;
  const int b   = bi / (64*NS);
  const int rem = bi % (64*NS);
  const int qt  = 63 - rem / NS;      // longest blocks dispatch first
  const int s   = rem % NS;

  const int ntiles = qt + 1;
  const int lo = ( s      * ntiles) / NS;
  const int hi = ((s + 1) * ntiles) / NS;
  const int pidx = (b*64 + qt)*NS + s;

  if (lo == hi){                      // empty split (block-uniform): weight 0
    if (l15 == 0){
      #pragma unroll
      for (int r=0;r<4;r++) pl[pidx*64 + w*16 + g*4 + r] = 0.0f;
    }
    return;
  }

  const long qbase = (long)b*TT + (long)qt*64;

  bf16x8 qf0, qf1;
  {
    const __bf16* src = qbg + (qbase + w*16 + l15)*HD + g*8;
    qf0 = *reinterpret_cast<const bf16x8*>(src);
    qf1 = *reinterpret_cast<const bf16x8*>(src + 32);
  }

  f32x4 o[4];
  #pragma unroll
  for (int ch=0; ch<4; ++ch) o[ch] = (f32x4)(0.0f);
  float lp[4] = {0.f, 0.f, 0.f, 0.f};

  const __bf16* vbase = vT + (size_t)b*64*TT;

  const int skey = tid >> 2;          // K row / V dim
  const int sd0  = (tid & 3) * 16;
  bf16x8 kr0, kr1, vr0, vr1;

  {
    const long kvbase = (long)b*TT + (long)lo*64;
    const __bf16* ks = kbg + (kvbase + skey)*HD + sd0;
    kr0 = *reinterpret_cast<const bf16x8*>(ks);
    kr1 = *reinterpret_cast<const bf16x8*>(ks+8);
    const __bf16* vs = vbase + (size_t)skey*TT + lo*64 + sd0;
    vr0 = *reinterpret_cast<const bf16x8*>(vs);
    vr1 = *reinterpret_cast<const bf16x8*>(vs+8);
  }

  for (int kv=lo; kv<hi; ++kv){
    __syncthreads();                  // previous tile fully consumed
    *reinterpret_cast<bf16x8*>(&Klds[skey][sd0])   = kr0;
    *reinterpret_cast<bf16x8*>(&Klds[skey][sd0+8]) = kr1;
    *reinterpret_cast<bf16x8*>(&Vlds[skey][sd0])   = vr0;
    *reinterpret_cast<bf16x8*>(&Vlds[skey][sd0+8]) = vr1;
    __syncthreads();

    if (kv+1 < hi){
      const long nbase = (long)b*TT + (long)(kv+1)*64;
      const __bf16* ks = kbg + (nbase + skey)*HD + sd0;
      kr0 = *reinterpret_cast<const bf16x8*>(ks);
      kr1 = *reinterpret_cast<const bf16x8*>(ks+8);
      const __bf16* vs = vbase + (size_t)skey*TT + (kv+1)*64 + sd0;
      vr0 = *reinterpret_cast<const bf16x8*>(vs);
      vr1 = *reinterpret_cast<const bf16x8*>(vs+8);
    }

    f32x4 sv[4];
    __builtin_amdgcn_s_setprio(1);
    #pragma unroll
    for (int c=0;c<4;c++){
      bf16x8 kb0 = *reinterpret_cast<const bf16x8*>(&Klds[c*16 + l15][g*8]);
      bf16x8 kb1 = *reinterpret_cast<const bf16x8*>(&Klds[c*16 + l15][g*8 + 32]);
      sv[c] = mfma16(qf0, kb0, (f32x4)(-16.0f));
      sv[c] = mfma16(qf1, kb1, sv[c]);
    }
    __builtin_amdgcn_s_setprio(0);

    if (kv == qt){   // diagonal tile: causal mask
      #pragma unroll
      for (int c=0;c<4;c++){
        const int key = c*16 + l15;
        #pragma unroll
        for (int r=0;r<4;r++){
          const int qr = w*16 + g*4 + r;
          if (key > qr) sv[c][r] = -1e30f;
        }
      }
    }

    #pragma unroll
    for (int c=0;c<4;c++){
      #pragma unroll
      for (int r=0;r<4;r++) sv[c][r] = __expf(sv[c][r]);
    }
    #pragma unroll
    for (int r=0;r<4;r++)
      lp[r] += (sv[0][r] + sv[1][r]) + (sv[2][r] + sv[3][r]);

    #pragma unroll
    for (int c=0;c<4;c++){
      #pragma unroll
      for (int r=0;r<4;r++) Plds[w][g*4+r][c*16 + l15] = (__bf16)sv[c][r];
    }
    asm volatile("s_waitcnt lgkmcnt(0)" ::: "memory");
    __builtin_amdgcn_sched_barrier(0);
    bf16x8 pa0 = *reinterpret_cast<const bf16x8*>(&Plds[w][l15][g*8]);
    bf16x8 pa1 = *reinterpret_cast<const bf16x8*>(&Plds[w][l15][g*8 + 32]);

    __builtin_amdgcn_s_setprio(1);
    #pragma unroll
    for (int ch=0; ch<4; ++ch){
      bf16x8 vb0 = *reinterpret_cast<const bf16x8*>(&Vlds[ch*16 + l15][g*8]);
      bf16x8 vb1 = *reinterpret_cast<const bf16x8*>(&Vlds[ch*16 + l15][g*8 + 32]);
      o[ch] = mfma16(pa0, vb0, o[ch]);
      o[ch] = mfma16(pa1, vb1, o[ch]);
    }
    __builtin_amdgcn_s_setprio(0);
  }

  float lr[4];
  #pragma unroll
  for (int r=0;r<4;r++){
    float v = lp[r];
    v += __shfl_xor(v, 1);
    v += __shfl_xor(v, 2);
    v += __shfl_xor(v, 4);
    v += __shfl_xor(v, 8);
    lr[r] = v;
  }
  float rl[4];
  #pragma unroll
  for (int r=0;r<4;r++) rl[r] = (lr[r] > 0.0f) ? 1.0f/lr[r] : 0.0f;

  __bf16* podst = po + (size_t)pidx*4096;
  #pragma unroll
  for (int ch=0; ch<4; ++ch){
    #pragma unroll
    for (int r=0;r<4;r++)
      podst[(w*16 + g*4 + r)*64 + ch*16 + l15] = (__bf16)(o[ch][r] * rl[r]);
  }
  if (l15 == 0){
    #pragma unroll
    for (int r=0;r<4;r++) pl[pidx*64 + w*16 + g*4 + r] = lr[r];
  }
}

// ---------- kernel 3: combine partials, vectorized (4 outputs/thread).
template<int NS>
__global__ __launch_bounds__(256) void comb_k(const __bf16* __restrict__ po,
    const float* __restrict__ pl, float* __restrict__ out){
  const int idx4  = (blockIdx.x*256 + threadIdx.x)*4;   // < 1048576
  const int qrow  = idx4 >> 6;
  const int dim0  = idx4 & 63;
  const int qtg   = qrow >> 6;
  const int rowin = qrow & 63;

  float num0=0.f, num1=0.f, num2=0.f, num3=0.f, den=0.f;
  #pragma unroll
  for (int s=0;s<NS;s++){
    const float lv = pl[(qtg*NS + s)*64 + rowin];
    den += lv;
    bf16x4 p4 = *reinterpret_cast<const bf16x4*>(
        po + (size_t)(qtg*NS + s)*4096 + rowin*64 + dim0);
    num0 += lv*(float)p4[0]; num1 += lv*(float)p4[1];
    num2 += lv*(float)p4[2]; num3 += lv*(float)p4[3];
  }
  const float rd = 1.0f/den;
  float4 o = make_float4(num0*rd, num1*rd, num2*rd, num3*rd);
  *reinterpret_cast<float4*>(out + idx4) = o;
}

extern "C" void kernel_launch(void* const* d_in, const int* in_sizes, int n_in,
                              void* d_out, int out_size, void* d_ws, size_t ws_size,
                              hipStream_t stream) {
  const float* x  = (const float*)d_in[0];
  const float* Wk = (const float*)d_in[2];
  const float* Wq = (const float*)d_in[3];
  const float* Wv = (const float*)d_in[4];
  float* out = (float*)d_out;

  char* ws = (char*)d_ws;
  __bf16* kb  = (__bf16*)(ws + 393216);              // 2 MiB
  __bf16* qb  = (__bf16*)(ws + 2490368);             // 2 MiB
  __bf16* vTb = (__bf16*)(ws + 4587520);             // 2 MiB
  __bf16* po  = (__bf16*)(ws + 6684672);

  proj_k<<<512, 512, 0, stream>>>(x, Wk, Wq, Wv, kb, qb, vTb);

  const size_t need8 = 6684672ull + (size_t)2048*4096*2 + (size_t)2048*64*4;
  if (ws_size >= need8){
    float* pl = (float*)(ws + 6684672 + (size_t)2048*4096*2);
    attn_part_k<8><<<2048, 256, 0, stream>>>(kb, qb, vTb, po, pl);
    comb_k<8>    <<<1024, 256, 0, stream>>>(po, pl, out);
  } else {
    float* pl = (float*)(ws + 6684672 + (size_t)1024*4096*2);
    attn_part_k<4><<<1024, 256, 0, stream>>>(kb, qb, vTb, po, pl);
    comb_k<4>    <<<1024, 256, 0, stream>>>(po, pl, out);
  }
}